// Round 2
// baseline (795.470 us; speedup 1.0000x reference)
//
#include <hip/hip_runtime.h>

// Problem constants
#define BB 64
#define TT 2048
#define HH 1024
#define AA 256
// GEMM: M = BB*TT = 131072, N = AA = 256, K = HH = 1024
#define M_TILE 32                  // rows per block (one b, 32 consecutive t)
#define N_CHUNKS (TT / M_TILE)     // 64 chunks per batch
#define NBLK (BB * TT / M_TILE)    // 4096 blocks
#define KSTEPS (HH / 32)           // 32 k-steps of 32
#define LDA 1032                   // LDS row stride in shorts (1024 + 8 pad)

typedef __attribute__((ext_vector_type(4))) float f32x4;
typedef __attribute__((ext_vector_type(8))) short s16x8;
typedef __attribute__((ext_vector_type(4))) short s16x4;

__device__ __forceinline__ short f2bf(float f) {
    // round-to-nearest-even fp32 -> bf16 (no NaN inputs here)
    unsigned int u = __float_as_uint(f);
    u += 0x7fffu + ((u >> 16) & 1u);
    return (short)(u >> 16);
}

__device__ __forceinline__ float bf2f(unsigned short u) {
    return __uint_as_float((unsigned int)u << 16);
}

__device__ __forceinline__ float fast_tanh(float x) {
    x = fminf(fmaxf(x, -10.f), 10.f);
    float e = __expf(2.f * x);
    return (e - 1.f) / (e + 1.f);
}

// ---------------------------------------------------------------------------
// Kernel 0: convert W [K=1024][N=256] fp32 -> bf16 B-fragment layout:
// wfrag[kk][q][n][j], k = kk*32 + q*8 + j. A lane (q,ln) loading 16 B at
// [kk][q][n=..+ln][0..7] gets exactly its MFMA B-operand fragment.
// ---------------------------------------------------------------------------
__global__ __launch_bounds__(256) void wconv_kernel(const float* __restrict__ w,
                                                    short* __restrict__ wfrag) {
    int t = blockIdx.x * 256 + threadIdx.x;   // 0..32767
    int kq = t >> 8;                          // kk*4 + q, 0..127
    int n  = t & 255;
    int kbase = kq * 8;
    s16x8 o;
#pragma unroll
    for (int j = 0; j < 8; ++j)
        o[j] = f2bf(w[(size_t)(kbase + j) * AA + n]);
    *(s16x8*)(wfrag + (size_t)t * 8) = o;
}

// ---------------------------------------------------------------------------
// Kernel 1: per 32-row tile (single X pass):
//   stage X-tile -> LDS bf16 (once) -> barrier-free MFMA K-loop (B from L2)
//   -> tanh·u scores -> chunk softmax -> weighted partial sum from LDS.
// ---------------------------------------------------------------------------
__global__ __launch_bounds__(512, 4) void score_pool_kernel(
    const float* __restrict__ X,      // [M][1024] fp32
    const short* __restrict__ wfrag,  // bf16 B frags, 512 KB (L2-resident)
    const float* __restrict__ bo,     // [256]
    const float* __restrict__ uo,     // [256]
    float* __restrict__ partials,     // [NBLK][1024]
    float* __restrict__ mstats)       // [NBLK][2] = {m_c, l_c}
{
    __shared__ __attribute__((aligned(16))) short ldsA[M_TILE * LDA]; // 64.5 KB
    __shared__ float lds_red[4][M_TILE];
    __shared__ float lds_w[M_TILE];

    const int tid  = threadIdx.x;       // 0..511
    const int wave = tid >> 6;          // 0..7
    const int lane = tid & 63;
    const int q    = lane >> 4;         // quad 0..3
    const int ln   = lane & 15;
    const int wm   = wave >> 2;         // row half: rows wm*16..+15
    const int wn   = wave & 3;          // col quarter: cols wn*64..+63
    const size_t m0 = (size_t)blockIdx.x * M_TILE;

    // ---- stage entire 32x1024 fp32 tile -> bf16 LDS (tile is contiguous) ----
    const float4* xt = (const float4*)(X + m0 * HH);
#pragma unroll
    for (int j = 0; j < 16; ++j) {
        int f = j * 512 + tid;          // float4 index, fully coalesced
        float4 v = xt[f];
        int row = f >> 8;               // 256 float4 per row
        int c4  = f & 255;
        s16x4 pk;
        pk[0] = f2bf(v.x); pk[1] = f2bf(v.y); pk[2] = f2bf(v.z); pk[3] = f2bf(v.w);
        *(s16x4*)&ldsA[row * LDA + c4 * 4] = pk;
    }
    __syncthreads();   // the ONLY barrier before the epilogue

    // ---- barrier-free K-loop: A from LDS, B from L2, 1-step SW pipeline ----
    f32x4 acc[4];
    const f32x4 zero = {0.f, 0.f, 0.f, 0.f};
#pragma unroll
    for (int nt = 0; nt < 4; ++nt) acc[nt] = zero;

    const int arow_off = (wm * 16 + ln) * LDA + q * 8;
    const size_t bbase = (size_t)q * 2048;   // + n*8 within a kk slab of 8192

    s16x8 a_cur = *(const s16x8*)&ldsA[arow_off];
    s16x8 b_cur[4];
#pragma unroll
    for (int nt = 0; nt < 4; ++nt) {
        int n = wn * 64 + nt * 16 + ln;
        b_cur[nt] = *(const s16x8*)(wfrag + bbase + (size_t)n * 8);
    }

    for (int kk = 0; kk < KSTEPS - 1; ++kk) {
        s16x8 a_nxt = *(const s16x8*)&ldsA[arow_off + (kk + 1) * 32];
        s16x8 b_nxt[4];
#pragma unroll
        for (int nt = 0; nt < 4; ++nt) {
            int n = wn * 64 + nt * 16 + ln;
            b_nxt[nt] = *(const s16x8*)(wfrag + (size_t)(kk + 1) * 8192 + bbase + (size_t)n * 8);
        }
#pragma unroll
        for (int nt = 0; nt < 4; ++nt)
            acc[nt] = __builtin_amdgcn_mfma_f32_16x16x32_bf16(a_cur, b_cur[nt], acc[nt], 0, 0, 0);
        a_cur = a_nxt;
#pragma unroll
        for (int nt = 0; nt < 4; ++nt) b_cur[nt] = b_nxt[nt];
    }
#pragma unroll
    for (int nt = 0; nt < 4; ++nt)
        acc[nt] = __builtin_amdgcn_mfma_f32_16x16x32_bf16(a_cur, b_cur[nt], acc[nt], 0, 0, 0);

    // ---- scores = sum_n tanh(acc + b[n]) * u[n]; C layout row=q*4+r, col=ln ----
    float bv[4], uv[4];
#pragma unroll
    for (int nt = 0; nt < 4; ++nt) {
        int n = wn * 64 + nt * 16 + ln;
        bv[nt] = bo[n];
        uv[nt] = uo[n];
    }
#pragma unroll
    for (int r = 0; r < 4; ++r) {
        float v = 0.f;
#pragma unroll
        for (int nt = 0; nt < 4; ++nt)
            v += fast_tanh(acc[nt][r] + bv[nt]) * uv[nt];
        v += __shfl_xor(v, 1);
        v += __shfl_xor(v, 2);
        v += __shfl_xor(v, 4);
        v += __shfl_xor(v, 8);
        if (ln == 0) lds_red[wn][wm * 16 + q * 4 + r] = v;
    }
    __syncthreads();

    // ---- chunk-local softmax over the 32 rows ----
    if (tid < M_TILE) {
        float sv = lds_red[0][tid] + lds_red[1][tid] + lds_red[2][tid] + lds_red[3][tid];
        float mx = sv;
        mx = fmaxf(mx, __shfl_xor(mx, 1));
        mx = fmaxf(mx, __shfl_xor(mx, 2));
        mx = fmaxf(mx, __shfl_xor(mx, 4));
        mx = fmaxf(mx, __shfl_xor(mx, 8));
        mx = fmaxf(mx, __shfl_xor(mx, 16));
        float wv = __expf(sv - mx);
        float ls = wv;
        ls += __shfl_xor(ls, 1);
        ls += __shfl_xor(ls, 2);
        ls += __shfl_xor(ls, 4);
        ls += __shfl_xor(ls, 8);
        ls += __shfl_xor(ls, 16);
        lds_w[tid] = wv;
        if (tid == 0) {
            mstats[2 * blockIdx.x]     = mx;
            mstats[2 * blockIdx.x + 1] = ls;
        }
    }
    __syncthreads();

    // ---- weighted partial sum from LDS (no second HBM pass) ----
    // thread tid handles cols 2*tid, 2*tid+1; lanes read consecutive words.
    float ox = 0.f, oy = 0.f;
    const int cbyte = tid * 4;  // byte offset of col pair within a row
#pragma unroll 8
    for (int t = 0; t < M_TILE; ++t) {
        float wt = lds_w[t];
        unsigned int pk = *(const unsigned int*)((const char*)ldsA + (size_t)t * (LDA * 2) + cbyte);
        ox += wt * bf2f((unsigned short)(pk & 0xffffu));
        oy += wt * bf2f((unsigned short)(pk >> 16));
    }
    float2 o2 = {ox, oy};
    *(float2*)(partials + (size_t)blockIdx.x * HH + tid * 2) = o2;
}

// ---------------------------------------------------------------------------
// Kernel 2: combine 64 chunks per batch with global softmax rescaling.
// ---------------------------------------------------------------------------
__global__ __launch_bounds__(256) void combine_kernel(
    const float* __restrict__ partials,
    const float* __restrict__ mstats,
    float* __restrict__ out)
{
    int b = blockIdx.x;
    int tid = threadIdx.x;
    float M = -1e30f;
#pragma unroll
    for (int c = 0; c < N_CHUNKS; ++c)
        M = fmaxf(M, mstats[2 * (b * N_CHUNKS + c)]);
    float denom = 0.f;
    float4 o = {0.f, 0.f, 0.f, 0.f};
#pragma unroll 4
    for (int c = 0; c < N_CHUNKS; ++c) {
        int ch = b * N_CHUNKS + c;
        float sc = __expf(mstats[2 * ch] - M);
        denom += sc * mstats[2 * ch + 1];
        float4 p = *(const float4*)(partials + (size_t)ch * HH + tid * 4);
        o.x += sc * p.x;
        o.y += sc * p.y;
        o.z += sc * p.z;
        o.w += sc * p.w;
    }
    float inv = 1.f / denom;
    float* orow = out + (size_t)b * (HH + 1) + tid * 4;  // row stride 1025
    orow[0] = o.x * inv;
    orow[1] = o.y * inv;
    orow[2] = o.z * inv;
    orow[3] = o.w * inv;
    if (tid == 0) out[(size_t)b * (HH + 1) + HH] = 1.0f;
}

// ---------------------------------------------------------------------------
extern "C" void kernel_launch(void* const* d_in, const int* in_sizes, int n_in,
                              void* d_out, int out_size, void* d_ws, size_t ws_size,
                              hipStream_t stream) {
    const float* X  = (const float*)d_in[0];  // [64,2048,1024]
    const float* w  = (const float*)d_in[1];  // [1024,256]
    const float* bo = (const float*)d_in[2];  // [256]
    const float* uo = (const float*)d_in[3];  // [256]
    float* out = (float*)d_out;               // [64,1025]

    char* ws = (char*)d_ws;
    short* wfrag    = (short*)ws;                                   // 512 KB
    float* partials = (float*)(ws + (512u << 10));                  // 16 MB
    float* mstats   = (float*)(ws + (512u << 10) + (16u << 20));    // 32 KB

    wconv_kernel<<<128, 256, 0, stream>>>(w, wfrag);
    score_pool_kernel<<<NBLK, 512, 0, stream>>>(X, wfrag, bo, uo, partials, mstats);
    combine_kernel<<<BB, 256, 0, stream>>>(partials, mstats, out);
}